// Round 1
// baseline (269.100 us; speedup 1.0000x reference)
//
#include <hip/hip_runtime.h>

#define BM 256
#define BN 128
#define BK 64
#define ASZ (BM * BK)        // 16384 fp16 = 32 KB
#define BSZ (BN * BK)        // 8192  fp16 = 16 KB
#define SLOT (ASZ + BSZ)     // 24576 fp16 = 48 KB per ring slot

typedef __attribute__((ext_vector_type(8))) _Float16 half8;   // MFMA A/B frag
typedef __attribute__((ext_vector_type(2))) __fp16 h2raw;     // cvt_pkrtz result
typedef __attribute__((ext_vector_type(4))) float floatx4;    // MFMA C/D frag
typedef __attribute__((ext_vector_type(4))) float f4;         // raw float4

#define AS1U(p) ((const __attribute__((address_space(1))) unsigned int*)(p))
#define AS3U(p) ((__attribute__((address_space(3))) unsigned int*)(p))

// ---------- prepass: fp32 -> fp16 for x AND W in one dispatch ----------
__global__ __launch_bounds__(256) void cvt_fp32_fp16_2(
        const float* __restrict__ x, _Float16* __restrict__ xh, int nx8,
        const float* __restrict__ W, _Float16* __restrict__ wh, int nw8,
        int xblocks) {
    const f4* s4;
    half8* d8;
    int n8, i, stride;
    if ((int)blockIdx.x < xblocks) {
        s4 = (const f4*)x; d8 = (half8*)xh; n8 = nx8;
        i = blockIdx.x * blockDim.x + threadIdx.x;
        stride = xblocks * blockDim.x;
    } else {
        s4 = (const f4*)W; d8 = (half8*)wh; n8 = nw8;
        i = (blockIdx.x - xblocks) * blockDim.x + threadIdx.x;
        stride = (gridDim.x - xblocks) * blockDim.x;
    }
    union { h2raw h2[4]; half8 h8; } u;
    for (; i < n8; i += stride) {
        f4 a = s4[2 * i];
        f4 b = s4[2 * i + 1];
        u.h2[0] = __builtin_amdgcn_cvt_pkrtz(a.x, a.y);
        u.h2[1] = __builtin_amdgcn_cvt_pkrtz(a.z, a.w);
        u.h2[2] = __builtin_amdgcn_cvt_pkrtz(b.x, b.y);
        u.h2[3] = __builtin_amdgcn_cvt_pkrtz(b.z, b.w);
        d8[i] = u.h8;
    }
}

// ---------- fused fp16 GEMM + gumbel-sigmoid epilogue ----------
// C[m][n] = sum_k x[m][k]*W[n][k];  out = sigmoid((C + b + g1 - g2)/0.1)
// 256x128 tile, 8 waves (2x2 wave-tile 64x64 each ... wave grid 4Mx2N),
// ring-3 LDS K-pipeline with counted vmcnt(12) (T3/T4), setprio (T5).
__global__ __launch_bounds__(512, 2) void gumbel_fused(
        const _Float16* __restrict__ xh, const _Float16* __restrict__ wh,
        const float* __restrict__ bias, const float* __restrict__ u1,
        const float* __restrict__ u2, float* __restrict__ out,
        int M, int N, int K) {
    // 3-slot ring: slot s at Smem + s*SLOT (A then B). 144 KB total.
    // Epilogue scratch (8 waves x 1280 f32 = 40 KB) lives inside slot 0,
    // which is safe: tail junk prefetches only target slots 1 and 2.
    __shared__ _Float16 Smem[3 * SLOT];

    const int tid  = threadIdx.x;
    const int lane = tid & 63;
    const int wave = tid >> 6;            // 0..7

    // Bijective XCD swizzle: 512 wgs, 64 per XCD. Within an XCD, consecutive
    // locals enumerate bx fastest -> all 8 sharers of an A row-panel (512 KB)
    // are co-resident on one XCD L2 (4 panels + 2 MB W = 4 MB).
    const int nbx = N / BN;               // 8
    const int bid = blockIdx.x;
    const int per = gridDim.x >> 3;       // 64
    const int vid = (bid & 7) * per + (bid >> 3);
    const int by  = vid / nbx;
    const int bx  = vid - by * nbx;
    const int bm  = by * BM;
    const int bn  = bx * BN;

    // --- staging: A = 2048 16B chunks (4/thread), B = 1024 (2/thread).
    // Chunk s -> row r = s>>3, global chunk col cc = (s&7)^(r&7): swizzle on
    // the GLOBAL side, LDS stays linear (global_load_lds = base + lane*16).
    int aoff[4], lsA[4], boff[2], lsB[2];
#pragma unroll
    for (int rep = 0; rep < 4; rep++) {
        int s = rep * 512 + tid;          // 0..2047
        int r = s >> 3;                   // 0..255
        int cc = (s & 7) ^ (r & 7);
        aoff[rep] = (bm + r) * K + cc * 8;
        lsA[rep] = s * 8;
    }
#pragma unroll
    for (int rep = 0; rep < 2; rep++) {
        int s = rep * 512 + tid;          // 0..1023
        int r = s >> 3;                   // 0..127
        int cc = (s & 7) ^ (r & 7);
        boff[rep] = (bn + r) * K + cc * 8;
        lsB[rep] = s * 8;
    }

    // --- fragment addressing (16x16x32: A[m=lane&15][k=(lane>>4)*8+j]) ---
    const int r16  = lane & 15;
    const int quad = lane >> 4;
    const int wr = wave >> 1;             // 0..3 (M dir)
    const int wc = wave & 1;              // 0..1 (N dir)
    const int wm = wr * 64;
    const int wn = wc * 64;

    int aro[4][2], bro[4][2];
#pragma unroll
    for (int i = 0; i < 4; i++) {
        int ra = wm + i * 16 + r16;
        int rb = wn + i * 16 + r16;
#pragma unroll
        for (int s = 0; s < 2; s++) {
            aro[i][s] = ra * BK + (((s * 4 + quad) ^ (ra & 7)) * 8);
            bro[i][s] = rb * BK + (((s * 4 + quad) ^ (rb & 7)) * 8);
        }
    }

    floatx4 acc[4][4] = {};
    const int KT = K / BK;                // 16

    // --- prologue: stage tiles 0,1 into slots 0,1 (12 loads in flight) ---
#pragma unroll
    for (int t0 = 0; t0 < 2; t0++) {
        _Float16* Ap = Smem + t0 * SLOT;
        _Float16* Bp = Ap + ASZ;
        int kb = t0 * BK;
#pragma unroll
        for (int rep = 0; rep < 4; rep++)
            __builtin_amdgcn_global_load_lds(AS1U(xh + aoff[rep] + kb), AS3U(Ap + lsA[rep]), 16, 0, 0);
#pragma unroll
        for (int rep = 0; rep < 2; rep++)
            __builtin_amdgcn_global_load_lds(AS1U(wh + boff[rep] + kb), AS3U(Bp + lsB[rep]), 16, 0, 0);
    }

    int sc = 0;                           // compute slot = t % 3
    for (int t = 0; t < KT; t++) {
        // issue tile t+2 into slot (t+2)%3 (its previous occupant, tile t-1,
        // was consumed before the previous end-barrier). For the last two
        // iterations issue clamped junk re-loads of tile KT-1 so the counted
        // vmcnt below stays uniform; they land in slots 1/2, never read.
        {
            int tp = (t + 2 < KT) ? (t + 2) : (KT - 1);
            int sp = sc + 2; if (sp >= 3) sp -= 3;
            _Float16* Ap = Smem + sp * SLOT;
            _Float16* Bp = Ap + ASZ;
            int kb = tp * BK;
#pragma unroll
            for (int rep = 0; rep < 4; rep++)
                __builtin_amdgcn_global_load_lds(AS1U(xh + aoff[rep] + kb), AS3U(Ap + lsA[rep]), 16, 0, 0);
#pragma unroll
            for (int rep = 0; rep < 2; rep++)
                __builtin_amdgcn_global_load_lds(AS1U(wh + boff[rep] + kb), AS3U(Bp + lsB[rep]), 16, 0, 0);
        }
        // counted wait: leaves tiles t+1,t+2 (12 loads) in flight; everything
        // older (tile t) has landed. Raw barrier: no compiler vmcnt(0) drain.
        asm volatile("s_waitcnt vmcnt(12)" ::: "memory");
        __builtin_amdgcn_sched_barrier(0);
        __builtin_amdgcn_s_barrier();

        const _Float16* As = Smem + sc * SLOT;
        const _Float16* Bs = As + ASZ;

        half8 bf[4][2];
#pragma unroll
        for (int j = 0; j < 4; j++)
#pragma unroll
            for (int s = 0; s < 2; s++)
                bf[j][s] = *(const half8*)(Bs + bro[j][s]);
#pragma unroll
        for (int i = 0; i < 4; i++) {
            half8 a0 = *(const half8*)(As + aro[i][0]);
            half8 a1 = *(const half8*)(As + aro[i][1]);
            __builtin_amdgcn_s_setprio(1);
#pragma unroll
            for (int j = 0; j < 4; j++) {
                acc[i][j] = __builtin_amdgcn_mfma_f32_16x16x32_f16(a0, bf[j][0], acc[i][j], 0, 0, 0);
                acc[i][j] = __builtin_amdgcn_mfma_f32_16x16x32_f16(a1, bf[j][1], acc[i][j], 0, 0, 0);
            }
            __builtin_amdgcn_s_setprio(0);
        }
        // all ds_reads above were consumed by MFMAs (compiler lgkm waits),
        // so the raw barrier is safe; keep 12 loads in flight across it.
        __builtin_amdgcn_sched_barrier(0);
        __builtin_amdgcn_s_barrier();
        sc = sc + 1; if (sc >= 3) sc -= 3;
    }

    // --- epilogue (R6-verified transpose), now barrier-free: T is
    // wave-private, in-wave LDS ordering is enough. ---
    float* T = ((float*)Smem) + wave * 1280;
    const float inv_t = 10.0f;  // 1/TEMP

#pragma unroll
    for (int i = 0; i < 4; i++) {
        // make sure prior group's reads returned before overwriting T
        asm volatile("s_waitcnt lgkmcnt(0)" ::: "memory");
        __builtin_amdgcn_sched_barrier(0);
#pragma unroll
        for (int j = 0; j < 4; j++) {
            int col = j * 16 + r16;
            f4 v = {acc[i][j][0], acc[i][j][1], acc[i][j][2], acc[i][j][3]};
            *(f4*)(T + col * 20 + quad * 4) = v;
        }
#pragma unroll
        for (int rep = 0; rep < 2; rep++) {
#pragma unroll
            for (int rep2 = 0; rep2 < 2; rep2++) {
                int rr = (lane >> 3) + rep * 8;        // row in [0,16)
                int ch = (lane & 7) + rep2 * 8;        // float4 chunk in [0,16)
                int gm = bm + wm + i * 16 + rr;
                int gc = bn + wn + ch * 4;
                f4 l4;
                l4.x = T[(ch * 4 + 0) * 20 + rr];
                l4.y = T[(ch * 4 + 1) * 20 + rr];
                l4.z = T[(ch * 4 + 2) * 20 + rr];
                l4.w = T[(ch * 4 + 3) * 20 + rr];
                f4 bv = *(const f4*)(bias + gc);
                int idx = gm * N + gc;
                f4 v1 = __builtin_nontemporal_load((const f4*)(u1 + idx));
                f4 v2 = __builtin_nontemporal_load((const f4*)(u2 + idx));
                f4 o;
                {
                    float z = (l4.x + bv.x + __logf(__logf(v2.x) / __logf(v1.x))) * inv_t;
                    o.x = 1.0f / (1.0f + __expf(-z));
                }
                {
                    float z = (l4.y + bv.y + __logf(__logf(v2.y) / __logf(v1.y))) * inv_t;
                    o.y = 1.0f / (1.0f + __expf(-z));
                }
                {
                    float z = (l4.z + bv.z + __logf(__logf(v2.z) / __logf(v1.z))) * inv_t;
                    o.z = 1.0f / (1.0f + __expf(-z));
                }
                {
                    float z = (l4.w + bv.w + __logf(__logf(v2.w) / __logf(v1.w))) * inv_t;
                    o.w = 1.0f / (1.0f + __expf(-z));
                }
                __builtin_nontemporal_store(o, (f4*)(out + idx));
            }
        }
    }
}

extern "C" void kernel_launch(void* const* d_in, const int* in_sizes, int n_in,
                              void* d_out, int out_size, void* d_ws, size_t ws_size,
                              hipStream_t stream) {
    const float* x  = (const float*)d_in[0];
    const float* u1 = (const float*)d_in[1];
    const float* u2 = (const float*)d_in[2];
    const float* W  = (const float*)d_in[3];
    const float* b  = (const float*)d_in[4];
    float* out = (float*)d_out;

    const int N = in_sizes[4];            // 1024
    const int K = in_sizes[3] / N;        // 1024
    const int M = in_sizes[0] / K;        // 16384

    _Float16* xh = (_Float16*)d_ws;
    _Float16* wh = xh + (size_t)M * K;

    const int xblocks = 2048, wblocks = 256;
    cvt_fp32_fp16_2<<<xblocks + wblocks, 256, 0, stream>>>(
        x, xh, (M * K) / 8, W, wh, (N * K) / 8, xblocks);

    dim3 grid((M / BM) * (N / BN));       // 64 * 8 = 512
    gumbel_fused<<<grid, 512, 0, stream>>>(xh, wh, b, u1, u2, out, M, N, K);
}

// Round 2
// 256.198 us; speedup vs baseline: 1.0504x; 1.0504x over previous
//
#include <hip/hip_runtime.h>

#define BM 256
#define BN 256
#define BK 64
#define HALF 8192              // fp16 per half-slot (128 rows x 64 k)
#define PARITY 16384           // fp16 per parity region (2 halves)
#define BRING 32768            // B ring base (fp16): A ring = [0,32768)

typedef __attribute__((ext_vector_type(8))) _Float16 half8;   // MFMA A/B frag
typedef __attribute__((ext_vector_type(2))) __fp16 h2raw;     // cvt_pkrtz result
typedef __attribute__((ext_vector_type(4))) float floatx4;    // MFMA C/D frag
typedef __attribute__((ext_vector_type(4))) float f4;         // raw float4

#define AS1U(p) ((const __attribute__((address_space(1))) unsigned int*)(p))
#define AS3U(p) ((__attribute__((address_space(3))) unsigned int*)(p))

// ---------- prepass: fp32 -> fp16 for x AND W in one dispatch ----------
__global__ __launch_bounds__(256) void cvt_fp32_fp16_2(
        const float* __restrict__ x, _Float16* __restrict__ xh, int nx8,
        const float* __restrict__ W, _Float16* __restrict__ wh, int nw8,
        int xblocks) {
    const f4* s4;
    half8* d8;
    int n8, i, stride;
    if ((int)blockIdx.x < xblocks) {
        s4 = (const f4*)x; d8 = (half8*)xh; n8 = nx8;
        i = blockIdx.x * blockDim.x + threadIdx.x;
        stride = xblocks * blockDim.x;
    } else {
        s4 = (const f4*)W; d8 = (half8*)wh; n8 = nw8;
        i = (blockIdx.x - xblocks) * blockDim.x + threadIdx.x;
        stride = (gridDim.x - xblocks) * blockDim.x;
    }
    union { h2raw h2[4]; half8 h8; } u;
    for (; i < n8; i += stride) {
        f4 a = s4[2 * i];
        f4 b = s4[2 * i + 1];
        u.h2[0] = __builtin_amdgcn_cvt_pkrtz(a.x, a.y);
        u.h2[1] = __builtin_amdgcn_cvt_pkrtz(a.z, a.w);
        u.h2[2] = __builtin_amdgcn_cvt_pkrtz(b.x, b.y);
        u.h2[3] = __builtin_amdgcn_cvt_pkrtz(b.z, b.w);
        d8[i] = u.h8;
    }
}

// ---------- fused fp16 GEMM + gumbel-sigmoid epilogue ----------
// 256x256 tile, 8 waves (2M x 4N, wave tile 128x64), 4-phase-per-K-tile
// schedule (m201-style): 16 MFMA/phase, counted vmcnt(6) once per tile,
// ring-4 half-slots per operand (128 KB LDS), setprio around MFMA clusters.
__global__ __launch_bounds__(512, 2) void gumbel_fused(
        const _Float16* __restrict__ xh, const _Float16* __restrict__ wh,
        const float* __restrict__ bias, const float* __restrict__ u1,
        const float* __restrict__ u2, float* __restrict__ out,
        int M, int N, int K) {
    __shared__ _Float16 Smem[65536];   // 128 KB: A ring 64 KB | B ring 64 KB

    const int tid  = threadIdx.x;
    const int lane = tid & 63;
    const int wave = tid >> 6;            // 0..7

    // XCD swizzle: 256 wgs, 32 per XCD, consecutive vid -> same XCD so the
    // 4 sharers of each x row-panel (512 KB) hit one L2.
    const int bid = blockIdx.x;
    const int vid = (bid & 7) * (gridDim.x >> 3) + (bid >> 3);
    const int nbx = N / BN;               // 4
    const int by  = vid / nbx;
    const int bx  = vid - by * nbx;
    const int bm  = by * BM;
    const int bn  = bx * BN;

    // --- staging: tile = 2048 16B chunks per operand (4 loads/thread).
    // Chunk s: row r = s>>3, global chunk col cc = (s&7)^(r&7) (XOR on the
    // GLOBAL side; LDS linear since global_load_lds = base + lane*16).
    int aoff[4], boff[4], lsoff[4];
#pragma unroll
    for (int rep = 0; rep < 4; rep++) {
        int s = rep * 512 + tid;          // 0..2047
        int r = s >> 3;                   // 0..255  (rep>>1 = half)
        int cc = (s & 7) ^ (r & 7);
        aoff[rep] = (bm + r) * K + cc * 8;
        boff[rep] = (bn + r) * K + cc * 8;
        lsoff[rep] = s * 8;               // within parity region, fp16 elems
    }
#define STAGE_A(rep, ts, par) \
    __builtin_amdgcn_global_load_lds(AS1U(xh + aoff[rep] + (ts) * BK), \
        AS3U(Smem + (par) * PARITY + lsoff[rep]), 16, 0, 0)
#define STAGE_B(rep, ts, par) \
    __builtin_amdgcn_global_load_lds(AS1U(wh + boff[rep] + (ts) * BK), \
        AS3U(Smem + BRING + (par) * PARITY + lsoff[rep]), 16, 0, 0)

    // --- fragment addressing (16x16x32: A[m=lane&15][k=quad*8+j]) ---
    // k-slice s element chunk = s*4+quad, stored at col (s*4+quad)^(row&7).
    const int r16  = lane & 15;
    const int quad = lane >> 4;
    const int wr = wave >> 2;             // 0..1 (M): A half = wr
    const int wc = wave & 3;              // 0..3 (N): B half = wc>>1
    int arb[2], brb[2];
#pragma unroll
    for (int s = 0; s < 2; s++) {
        arb[s] = wr * HALF + r16 * 64 + ((s * 4 + quad) ^ (r16 & 7)) * 8;
        brb[s] = BRING + (wc >> 1) * HALF + ((wc & 1) * 64 + r16) * 64
               + ((s * 4 + quad) ^ (r16 & 7)) * 8;
    }

    floatx4 acc[8][4] = {};
    const int KT = K / BK;                // 16

    // --- prologue: tile0 A+B (parity 0), tile1 A (parity 1): 12 loads ---
#pragma unroll
    for (int rep = 0; rep < 4; rep++) STAGE_A(rep, 0, 0);
#pragma unroll
    for (int rep = 0; rep < 4; rep++) STAGE_B(rep, 0, 0);
#pragma unroll
    for (int rep = 0; rep < 4; rep++) STAGE_A(rep, 1, 1);

    for (int t = 0; t < KT; t++) {
        const int p  = t & 1;
        const int pn = p ^ 1;
        const int t1 = (t + 1 < KT) ? t + 1 : KT - 1;   // junk-clamped tail
        const int t2 = (t + 2 < KT) ? t + 2 : KT - 1;
        const _Float16* Sp = Smem + p * PARITY;
        half8 a[8][2], b[4][2];

        // ---- P1: stage B(t+1) 0,1 | vmcnt(6) | bar | 12 ds_read | MFMA q0 s0
        STAGE_B(0, t1, pn); STAGE_B(1, t1, pn);
        asm volatile("s_waitcnt vmcnt(6)" ::: "memory");
        __builtin_amdgcn_sched_barrier(0);
        __builtin_amdgcn_s_barrier();
        __builtin_amdgcn_sched_barrier(0);
#pragma unroll
        for (int i = 0; i < 4; i++) {
            a[i][0] = *(const half8*)(Sp + arb[0] + i * 1024);
            a[i][1] = *(const half8*)(Sp + arb[1] + i * 1024);
        }
#pragma unroll
        for (int j = 0; j < 4; j++) b[j][0] = *(const half8*)(Sp + brb[0] + j * 1024);
        asm volatile("s_waitcnt lgkmcnt(0)" ::: "memory");
        __builtin_amdgcn_sched_barrier(0);
        __builtin_amdgcn_s_setprio(1);
#pragma unroll
        for (int i = 0; i < 4; i++)
#pragma unroll
            for (int j = 0; j < 4; j++)
                acc[i][j] = __builtin_amdgcn_mfma_f32_16x16x32_f16(a[i][0], b[j][0], acc[i][j], 0, 0, 0);
        __builtin_amdgcn_s_setprio(0);
        __builtin_amdgcn_sched_barrier(0);
        __builtin_amdgcn_s_barrier();

        // ---- P2: stage B(t+1) 2,3 | 12 ds_read | bar | MFMA q0 s1
        STAGE_B(2, t1, pn); STAGE_B(3, t1, pn);
#pragma unroll
        for (int i = 4; i < 8; i++) {
            a[i][0] = *(const half8*)(Sp + arb[0] + i * 1024);
            a[i][1] = *(const half8*)(Sp + arb[1] + i * 1024);
        }
#pragma unroll
        for (int j = 0; j < 4; j++) b[j][1] = *(const half8*)(Sp + brb[1] + j * 1024);
        __builtin_amdgcn_s_barrier();
        asm volatile("s_waitcnt lgkmcnt(0)" ::: "memory");
        __builtin_amdgcn_sched_barrier(0);
        __builtin_amdgcn_s_setprio(1);
#pragma unroll
        for (int i = 0; i < 4; i++)
#pragma unroll
            for (int j = 0; j < 4; j++)
                acc[i][j] = __builtin_amdgcn_mfma_f32_16x16x32_f16(a[i][1], b[j][1], acc[i][j], 0, 0, 0);
        __builtin_amdgcn_s_setprio(0);
        __builtin_amdgcn_sched_barrier(0);
        __builtin_amdgcn_s_barrier();
        // all of tile t's LDS is now in registers across every wave.

        // ---- P3: stage A(t+2) 0,1 into tile t's (now free) slots | MFMA q1 s0
        STAGE_A(0, t2, p); STAGE_A(1, t2, p);
        __builtin_amdgcn_s_setprio(1);
#pragma unroll
        for (int i = 4; i < 8; i++)
#pragma unroll
            for (int j = 0; j < 4; j++)
                acc[i][j] = __builtin_amdgcn_mfma_f32_16x16x32_f16(a[i][0], b[j][0], acc[i][j], 0, 0, 0);
        __builtin_amdgcn_s_setprio(0);
        __builtin_amdgcn_sched_barrier(0);
        __builtin_amdgcn_s_barrier();

        // ---- P4: stage A(t+2) 2,3 | MFMA q1 s1
        STAGE_A(2, t2, p); STAGE_A(3, t2, p);
        __builtin_amdgcn_s_setprio(1);
#pragma unroll
        for (int i = 4; i < 8; i++)
#pragma unroll
            for (int j = 0; j < 4; j++)
                acc[i][j] = __builtin_amdgcn_mfma_f32_16x16x32_f16(a[i][1], b[j][1], acc[i][j], 0, 0, 0);
        __builtin_amdgcn_s_setprio(0);
        __builtin_amdgcn_sched_barrier(0);
        __builtin_amdgcn_s_barrier();
    }

    // --- drain tail junk prefetches before reusing LDS as scratch ---
    asm volatile("s_waitcnt vmcnt(0)" ::: "memory");
    __builtin_amdgcn_sched_barrier(0);
    __builtin_amdgcn_s_barrier();

    // --- epilogue: per-wave 16x64 transpose groups through LDS, then
    // fully-coalesced f4 u1/u2/out accesses (R1-verified, barrier-free). ---
    float* T = ((float*)Smem) + wave * 1280;
    const float inv_t = 10.0f;  // 1/TEMP

#pragma unroll
    for (int i = 0; i < 8; i++) {
        // prior group's T reads must retire before overwriting (per-wave)
        asm volatile("s_waitcnt lgkmcnt(0)" ::: "memory");
        __builtin_amdgcn_sched_barrier(0);
#pragma unroll
        for (int j = 0; j < 4; j++) {
            int col = j * 16 + r16;
            f4 v = {acc[i][j][0], acc[i][j][1], acc[i][j][2], acc[i][j][3]};
            *(f4*)(T + col * 20 + quad * 4) = v;
        }
#pragma unroll
        for (int rep = 0; rep < 2; rep++) {
#pragma unroll
            for (int rep2 = 0; rep2 < 2; rep2++) {
                int rr = (lane >> 3) + rep * 8;        // row in [0,16)
                int ch = (lane & 7) + rep2 * 8;        // float4 chunk in [0,16)
                int gm = bm + wr * 128 + i * 16 + rr;
                int gc = bn + wc * 64 + ch * 4;
                f4 l4;
                l4.x = T[(ch * 4 + 0) * 20 + rr];
                l4.y = T[(ch * 4 + 1) * 20 + rr];
                l4.z = T[(ch * 4 + 2) * 20 + rr];
                l4.w = T[(ch * 4 + 3) * 20 + rr];
                f4 bv = *(const f4*)(bias + gc);
                int idx = gm * N + gc;
                f4 v1 = __builtin_nontemporal_load((const f4*)(u1 + idx));
                f4 v2 = __builtin_nontemporal_load((const f4*)(u2 + idx));
                f4 o;
                {
                    float z = (l4.x + bv.x + __logf(__logf(v2.x) / __logf(v1.x))) * inv_t;
                    o.x = 1.0f / (1.0f + __expf(-z));
                }
                {
                    float z = (l4.y + bv.y + __logf(__logf(v2.y) / __logf(v1.y))) * inv_t;
                    o.y = 1.0f / (1.0f + __expf(-z));
                }
                {
                    float z = (l4.z + bv.z + __logf(__logf(v2.z) / __logf(v1.z))) * inv_t;
                    o.z = 1.0f / (1.0f + __expf(-z));
                }
                {
                    float z = (l4.w + bv.w + __logf(__logf(v2.w) / __logf(v1.w))) * inv_t;
                    o.w = 1.0f / (1.0f + __expf(-z));
                }
                __builtin_nontemporal_store(o, (f4*)(out + idx));
            }
        }
    }
}

extern "C" void kernel_launch(void* const* d_in, const int* in_sizes, int n_in,
                              void* d_out, int out_size, void* d_ws, size_t ws_size,
                              hipStream_t stream) {
    const float* x  = (const float*)d_in[0];
    const float* u1 = (const float*)d_in[1];
    const float* u2 = (const float*)d_in[2];
    const float* W  = (const float*)d_in[3];
    const float* b  = (const float*)d_in[4];
    float* out = (float*)d_out;

    const int N = in_sizes[4];            // 1024
    const int K = in_sizes[3] / N;        // 1024
    const int M = in_sizes[0] / K;        // 16384

    _Float16* xh = (_Float16*)d_ws;
    _Float16* wh = xh + (size_t)M * K;

    const int xblocks = 2048, wblocks = 256;
    cvt_fp32_fp16_2<<<xblocks + wblocks, 256, 0, stream>>>(
        x, xh, (M * K) / 8, W, wh, (N * K) / 8, xblocks);

    dim3 grid((M / BM) * (N / BN));       // 64 * 4 = 256
    gumbel_fused<<<grid, 512, 0, stream>>>(xh, wh, b, u1, u2, out, M, N, K);
}